// Round 12
// baseline (177.375 us; speedup 1.0000x reference)
//
#include <hip/hip_runtime.h>
#include <hip/hip_bf16.h>
#include <math.h>

// Problem constants
#define NL 4096     // L patches
#define NQ 4096     // HS*WS pixels
#define SCALE 10.0f

typedef __bf16 bf16x8 __attribute__((ext_vector_type(8)));
typedef float  f32x4  __attribute__((ext_vector_type(4)));
typedef float  f32x4u __attribute__((ext_vector_type(4), aligned(4)));  // 4B-aligned vec load

#define GLOAD_LDS16(gp, lp)                                                        \
    __builtin_amdgcn_global_load_lds((const __attribute__((address_space(1))) void*)(gp), \
                                     (__attribute__((address_space(3))) void*)(lp), \
                                     16, 0, 0)

// ---------------------------------------------------------------------------
// K1: fused double-diagonal pass, round-12 structure.
// Each block computes 4 consecutive l (same hb, wb0..wb0+3) x all 4096 q.
// Interior taps: colb = q + (d-1)*64 is LINEAR in q -> per d only a 6-row
// window of aligned f32x4 loads; the +-1 column shifts come from neighbor
// lanes via shfl (halo for lane 0/63 via scalar loads). Rows shared across
// the 4 wb -> 2x fewer L2 bytes than the 1-wb version (which converged to
// ~65us across 3 codegens = traffic-bound).
// Col-wrap lanes (s2<0: d==0&&hs==0; s2>63: d==2&&hs==63) take a 2-unaligned-
// load window path with ws==0/63 element masks. Row-wrap (h2 out of range)
// uses Lbase 4031/1 with per-wb validity wm (verified round 6-8 semantics).
// ---------------------------------------------------------------------------
__global__ __launch_bounds__(256) void fuseD(const float* __restrict__ S,
                                             float* __restrict__ F) {
    int lin = blockIdx.x;
    int blk = (lin & 7) * 128 + (lin >> 3);   // bijective XCD chunking (1024%8==0)
    int l0 = blk * 4;
    int hb = l0 >> 6, wb0 = l0 & 63;          // wb0 in {0,4,...,60}
    int tid = threadIdx.x, lane = tid & 63;

    // block-uniform per-d row window base + per-wb validity
    int rowbase[3]; float wm[3][4];
    #pragma unroll
    for (int d = 0; d < 3; ++d) {
        int h2 = hb + d - 1;
        #pragma unroll
        for (int i = 0; i < 4; ++i) wm[d][i] = 1.f;
        if (h2 >= 0 && h2 <= 63) rowbase[d] = h2 * 64 + wb0;
        else if (h2 < 0) {
            rowbase[d] = 4031 + wb0;
            #pragma unroll
            for (int i = 0; i < 4; ++i) wm[d][i] = (wb0 + i >= 1) ? 1.f : 0.f;
        } else {
            rowbase[d] = 1 + wb0;
            #pragma unroll
            for (int i = 0; i < 4; ++i) wm[d][i] = (wb0 + i <= 62) ? 1.f : 0.f;
        }
    }

    for (int cc = 0; cc < 4; ++cc) {
        int q0 = (cc * 256 + tid) * 4;
        int hs = q0 >> 6, ws0 = q0 & 63;
        f32x4 z4 = {0.f, 0.f, 0.f, 0.f};
        f32x4 acc0 = z4, acc1 = z4, acc2 = z4, acc3 = z4;

        #pragma unroll
        for (int d = 0; d < 3; ++d) {
            int s2 = hs + d - 1;
            bool cw = (s2 < 0) || (s2 > 63);
            int colb = cw ? ((s2 < 0 ? 4031 : 1) + ws0) : (q0 + (d - 1) * 64);
            int cb = cw ? colb - 1 : colb;     // interior: aligned; wrap: window lo

            // 6-row window loads (row-guarded; cols always in-bounds by construction)
            f32x4 v[6], v2[6];
            #pragma unroll
            for (int r = 0; r < 6; ++r) {
                int rr = rowbase[d] - 1 + r;
                v[r] = z4;
                if (rr >= 0 && rr < 4096)
                    v[r] = *(const f32x4u*)(S + (size_t)rr * 4096 + cb);
            }
            if (cw) {
                #pragma unroll
                for (int r = 0; r < 6; ++r) {
                    int rr = rowbase[d] - 1 + r;
                    v2[r] = z4;
                    if (rr >= 0 && rr < 4096)
                        v2[r] = *(const f32x4u*)(S + (size_t)rr * 4096 + colb + 1);
                }
            }

            // interior cross-lane shifted elements
            float lm[4], rm[4];
            #pragma unroll
            for (int r = 0; r < 4; ++r) lm[r] = __shfl_up(v[r][3], 1);
            #pragma unroll
            for (int r = 0; r < 4; ++r) rm[r] = __shfl_down(v[r + 2][0], 1);
            if (!cw) {
                if (lane == 0 || colb == 0) {          // halo / flat left pad
                    #pragma unroll
                    for (int r = 0; r < 4; ++r) {
                        int rr = rowbase[d] - 1 + r;
                        lm[r] = (colb > 0 && rr >= 0 && rr < 4096)
                                ? S[(size_t)rr * 4096 + colb - 1] : 0.f;
                    }
                }
                if (lane == 63 || colb + 4 >= 4096) {  // halo / flat right pad
                    #pragma unroll
                    for (int r = 0; r < 4; ++r) {
                        int rr = rowbase[d] + 1 + r;
                        rm[r] = (colb + 4 < 4096 && rr >= 0 && rr < 4096)
                                ? S[(size_t)rr * 4096 + colb + 4] : 0.f;
                    }
                }
            }

            // per-wb tap sums: t[i] = L(row i) + C(row i+1) + R(row i+2)
            f32x4 t[4];
            if (!cw) {
                #pragma unroll
                for (int i = 0; i < 4; ++i) {
                    f32x4 Lv = { lm[i], v[i][0], v[i][1], v[i][2] };
                    f32x4 Cv = v[i + 1];
                    f32x4 Rv = { v[i + 2][1], v[i + 2][2], v[i + 2][3], rm[i] };
                    t[i] = Lv + Cv + Rv;
                }
            } else {
                #pragma unroll
                for (int i = 0; i < 4; ++i) {
                    f32x4 Lv = v[i];                                              // colb-1..+2
                    f32x4 Cv = { v[i+1][1], v[i+1][2], v[i+1][3], v2[i+1][2] };   // colb..+3
                    f32x4 Rv = v2[i + 2];                                         // colb+1..+4
                    t[i] = Lv + Cv + Rv;
                }
                if (s2 < 0 && ws0 == 0) { t[0][0] = 0.f; t[1][0] = 0.f; t[2][0] = 0.f; t[3][0] = 0.f; }
                if (s2 > 63 && ws0 == 60) { t[0][3] = 0.f; t[1][3] = 0.f; t[2][3] = 0.f; t[3][3] = 0.f; }
            }
            acc0 += wm[d][0] * t[0];
            acc1 += wm[d][1] * t[1];
            acc2 += wm[d][2] * t[2];
            acc3 += wm[d][3] * t[3];
        }
        *(f32x4*)(F + (size_t)(l0 + 0) * 4096 + q0) = acc0;
        *(f32x4*)(F + (size_t)(l0 + 1) * 4096 + q0) = acc1;
        *(f32x4*)(F + (size_t)(l0 + 2) * 4096 + q0) = acc2;
        *(f32x4*)(F + (size_t)(l0 + 3) * 4096 + q0) = acc3;
    }
}

// ---------------------------------------------------------------------------
// S1: partial softmax stats on F[l][q] (column softmax).
// ---------------------------------------------------------------------------
__global__ __launch_bounds__(256) void softPart(const float* __restrict__ F,
                                                const float* __restrict__ mm,
                                                float* __restrict__ Pm,
                                                float* __restrict__ Ps) {
    int qt = blockIdx.x, lc = blockIdx.y;
    int qo = threadIdx.x & 63, lg = threadIdx.x >> 6;
    int q = qt * 64 + qo;
    __shared__ float red[4][64];

    float sv[32];
    float m = -1e30f;
    #pragma unroll
    for (int i = 0; i < 32; ++i) {
        int l = lc * 128 + i * 4 + lg;
        float s = F[(size_t)l * 4096 + q] * mm[l] * SCALE;
        sv[i] = s;
        m = fmaxf(m, s);
    }
    red[lg][qo] = m;
    __syncthreads();
    m = fmaxf(fmaxf(red[0][qo], red[1][qo]), fmaxf(red[2][qo], red[3][qo]));
    __syncthreads();

    float sum = 0.f;
    #pragma unroll
    for (int i = 0; i < 32; ++i) sum += __expf(sv[i] - m);
    red[lg][qo] = sum;
    __syncthreads();
    if (lg == 0) {
        sum = red[0][qo] + red[1][qo] + red[2][qo] + red[3][qo];
        Pm[lc * 4096 + q] = m;
        Ps[lc * 4096 + q] = sum;
    }
}

// ---------------------------------------------------------------------------
// S2: combine 32 chunk partials per q.
// ---------------------------------------------------------------------------
__global__ void softComb(const float* __restrict__ Pm, const float* __restrict__ Ps,
                         float* __restrict__ Qm, float* __restrict__ Qi) {
    int q = blockIdx.x * 256 + threadIdx.x;
    float M = -1e30f;
    #pragma unroll
    for (int i = 0; i < 32; ++i) M = fmaxf(M, Pm[i * 4096 + q]);
    float S = 0.f;
    #pragma unroll
    for (int i = 0; i < 32; ++i) S += Ps[i * 4096 + q] * __expf(Pm[i * 4096 + q] - M);
    Qm[q] = M;
    Qi[q] = 1.0f / S;
}

// ---------------------------------------------------------------------------
// S3: normalize + bf16 convert + transpose. Pt[m=q][k=l] = bf16(P[l][q]).
// ---------------------------------------------------------------------------
__global__ __launch_bounds__(256) void normTransP(const float* __restrict__ F,
                                                  const float* __restrict__ mm,
                                                  const float* __restrict__ Qm,
                                                  const float* __restrict__ Qi,
                                                  __hip_bfloat16* __restrict__ Pt) {
    __shared__ float T[64][65];
    int qt = blockIdx.x, lt = blockIdx.y;
    int c = threadIdx.x & 63;
    int q = qt * 64 + c;
    float qm = Qm[q], qi = Qi[q];
    #pragma unroll
    for (int p = 0; p < 16; ++p) {
        int r = p * 4 + (threadIdx.x >> 6);
        int l = lt * 64 + r;
        float mml = mm[l];
        float s = F[(size_t)l * 4096 + q] * mml * SCALE - qm;
        T[r][c] = mml * __expf(s) * qi;
    }
    __syncthreads();
    #pragma unroll
    for (int p = 0; p < 16; ++p) {
        int r = p * 4 + (threadIdx.x >> 6);
        Pt[(size_t)(qt * 64 + r) * 4096 + lt * 64 + c] = (__hip_bfloat16)T[c][r];
    }
}

// ---------------------------------------------------------------------------
// Wt: transpose + convert raw_w [k][ck] fp32 -> Wt [n][k] bf16, with the
// GEMM N-dim permuted as n = kyx*64 + c (so scatterD reads Mo coalesced).
// ---------------------------------------------------------------------------
__global__ __launch_bounds__(256) void transW(const float* __restrict__ Wsrc,
                                              __hip_bfloat16* __restrict__ Wt) {
    __shared__ float T[64][65];
    int nt = blockIdx.x, kt = blockIdx.y;
    int c = threadIdx.x & 63;
    #pragma unroll
    for (int p = 0; p < 16; ++p) {
        int r = p * 4 + (threadIdx.x >> 6);
        T[r][c] = Wsrc[(size_t)(kt * 64 + r) * 1024 + nt * 64 + c];
    }
    __syncthreads();
    #pragma unroll
    for (int p = 0; p < 16; ++p) {
        int r = p * 4 + (threadIdx.x >> 6);   // r = ck_local; ck = nt*64 + r
        int n_new = (r & 15) * 64 + nt * 4 + (r >> 4);   // kyx*64 + c_chan
        Wt[(size_t)n_new * 4096 + kt * 64 + c] = (__hip_bfloat16)T[c][r];
    }
}

// ---------------------------------------------------------------------------
// Wc prep: conv weight [co][ci][3][3] fp32 -> Wc[kyx][co][ci] bf16.
// ---------------------------------------------------------------------------
__global__ void transWc(const float* __restrict__ Wsrc, __hip_bfloat16* __restrict__ Wd) {
    int t = blockIdx.x * 256 + threadIdx.x;   // kyx*4096 + co*64 + ci
    int kyx = t >> 12;
    int co = (t >> 6) & 63;
    int ci = t & 63;
    Wd[t] = (__hip_bfloat16)Wsrc[co * 576 + ci * 9 + kyx];
}

// ---------------------------------------------------------------------------
// K4: bf16 MFMA GEMM, K-SPLIT x2. 128x128 tile, BK=32, 4 waves (2x2).
// Grid = 512 = 2 blocks/CU. XCD-chunked remap; both-sides XOR swizzle.
// ---------------------------------------------------------------------------
__global__ __launch_bounds__(256) void gemmMfmaK(const __hip_bfloat16* __restrict__ Ab,
                                                 const __hip_bfloat16* __restrict__ Bb,
                                                 float* __restrict__ C0,
                                                 float* __restrict__ C1) {
    __shared__ __align__(16) __hip_bfloat16 As[2][128][32];  // 16 KiB
    __shared__ __align__(16) __hip_bfloat16 Bs[2][128][32];  // 16 KiB
    int lin = blockIdx.x;
    int wid = (lin & 7) * 64 + (lin >> 3);    // XCD chunking
    int bm = wid & 31;
    int bn = (wid >> 5) & 7;
    int bz = wid >> 8;
    int bm0 = bm * 128, bn0 = bn * 128;
    size_t kbase = (size_t)bz * 2048;
    float* Cm = bz ? C1 : C0;

    int tid = threadIdx.x;
    int lane = tid & 63, w = tid >> 6;
    int wm = (w >> 1) * 64, wn = (w & 1) * 64;

    int srow = w * 32 + (lane >> 2);
    int scol = (((lane & 3) ^ ((lane >> 3) & 3))) * 8;   // swizzled source col
    const __hip_bfloat16* ga0 = Ab + (size_t)(bm0 + srow) * 4096 + kbase + scol;
    const __hip_bfloat16* ga1 = Ab + (size_t)(bm0 + srow + 16) * 4096 + kbase + scol;
    const __hip_bfloat16* gb0 = Bb + (size_t)(bn0 + srow) * 4096 + kbase + scol;
    const __hip_bfloat16* gb1 = Bb + (size_t)(bn0 + srow + 16) * 4096 + kbase + scol;

    f32x4 acc[4][4] = {};
    int fm = lane & 15;
    int fkz = (((lane >> 4) ^ ((lane >> 1) & 3))) * 8;   // swizzled k-offset

    GLOAD_LDS16(ga0, &As[0][w * 32][0]);
    GLOAD_LDS16(ga1, &As[0][w * 32 + 16][0]);
    GLOAD_LDS16(gb0, &Bs[0][w * 32][0]);
    GLOAD_LDS16(gb1, &Bs[0][w * 32 + 16][0]);
    __syncthreads();

    int buf = 0;
    for (int t = 0; t < 64; ++t) {
        if (t + 1 < 64) {
            int k0 = (t + 1) * 32;
            GLOAD_LDS16(ga0 + k0, &As[buf ^ 1][w * 32][0]);
            GLOAD_LDS16(ga1 + k0, &As[buf ^ 1][w * 32 + 16][0]);
            GLOAD_LDS16(gb0 + k0, &Bs[buf ^ 1][w * 32][0]);
            GLOAD_LDS16(gb1 + k0, &Bs[buf ^ 1][w * 32 + 16][0]);
        }
        bf16x8 af[4], bfr[4];
        #pragma unroll
        for (int i = 0; i < 4; ++i)
            af[i] = *(const bf16x8*)&As[buf][wm + i * 16 + fm][fkz];
        #pragma unroll
        for (int j = 0; j < 4; ++j)
            bfr[j] = *(const bf16x8*)&Bs[buf][wn + j * 16 + fm][fkz];
        #pragma unroll
        for (int i = 0; i < 4; ++i)
            #pragma unroll
            for (int j = 0; j < 4; ++j)
                acc[i][j] = __builtin_amdgcn_mfma_f32_16x16x32_bf16(af[i], bfr[j], acc[i][j], 0, 0, 0);
        __syncthreads();
        buf ^= 1;
    }

    // D mapping: col = lane&15, row = (lane>>4)*4 + reg  [HW-verified]
    #pragma unroll
    for (int i = 0; i < 4; ++i) {
        #pragma unroll
        for (int j = 0; j < 4; ++j) {
            int row = bm0 + wm + i * 16 + (lane >> 4) * 4;
            int col = bn0 + wn + j * 16 + (lane & 15);
            #pragma unroll
            for (int r = 0; r < 4; ++r)
                Cm[(size_t)(row + r) * 1024 + col] = acc[i][j][r];
        }
    }
}

// ---------------------------------------------------------------------------
// K5: transposed-conv gather + /4, summing the two K-split halves ->
// padded NHWC bf16 Xp[130][130][64].
// ---------------------------------------------------------------------------
__global__ void scatterD(const float* __restrict__ Mo, const float* __restrict__ Mo2,
                         __hip_bfloat16* __restrict__ Xp) {
    int c = threadIdx.x & 63;
    int pix = blockIdx.x * 4 + (threadIdx.x >> 6);
    int ox = pix & 127, oy = pix >> 7;
    float acc = 0.f;
    #pragma unroll
    for (int ky = 0; ky < 4; ++ky) {
        int ty = oy + 1 - ky;
        if (ty & 1) continue;
        int iy = ty >> 1;
        if (iy < 0 || iy >= 64) continue;
        #pragma unroll
        for (int kx = 0; kx < 4; ++kx) {
            int txx = ox + 1 - kx;
            if (txx & 1) continue;
            int ix = txx >> 1;
            if (ix < 0 || ix >= 64) continue;
            size_t off = (size_t)(iy * 64 + ix) * 1024 + (ky * 4 + kx) * 64 + c;
            acc += Mo[off] + Mo2[off];
        }
    }
    Xp[((size_t)(oy + 1) * 130 + ox + 1) * 64 + c] = (__hip_bfloat16)(acc * 0.25f);
}

// ---------------------------------------------------------------------------
// K6/K7: 3x3 conv + bias + ELU as 9-offset implicit MFMA GEMM.
// ---------------------------------------------------------------------------
template <int MODE>
__global__ __launch_bounds__(256) void convMfma(const __hip_bfloat16* __restrict__ Xp,
                                                const __hip_bfloat16* __restrict__ Wc,
                                                const float* __restrict__ Bi,
                                                __hip_bfloat16* __restrict__ Yp,
                                                float* __restrict__ Yo) {
    int tid = threadIdx.x, lane = tid & 63, w = tid >> 6;
    int y = blockIdx.x >> 1, x0 = (blockIdx.x & 1) * 64;
    int co0 = w * 16;
    int fl = lane & 15, fh = lane >> 4;

    bf16x8 wb[3][3][2];
    #pragma unroll
    for (int ky = 0; ky < 3; ++ky)
        #pragma unroll
        for (int kx = 0; kx < 3; ++kx)
            #pragma unroll
            for (int kc = 0; kc < 2; ++kc)
                wb[ky][kx][kc] = *(const bf16x8*)&Wc[(size_t)((ky * 3 + kx) * 64 + co0 + fl) * 64 + kc * 32 + fh * 8];

    f32x4 acc[4] = {};
    #pragma unroll
    for (int ky = 0; ky < 3; ++ky) {
        #pragma unroll
        for (int kx = 0; kx < 3; ++kx) {
            const __hip_bfloat16* xrow = Xp + ((size_t)(y + ky) * 130 + x0 + kx) * 64;
            #pragma unroll
            for (int kc = 0; kc < 2; ++kc) {
                #pragma unroll
                for (int mt = 0; mt < 4; ++mt) {
                    bf16x8 af = *(const bf16x8*)&xrow[(mt * 16 + fl) * 64 + kc * 32 + fh * 8];
                    acc[mt] = __builtin_amdgcn_mfma_f32_16x16x32_bf16(af, wb[ky][kx][kc], acc[mt], 0, 0, 0);
                }
            }
        }
    }

    float bias = Bi[co0 + fl];
    #pragma unroll
    for (int mt = 0; mt < 4; ++mt) {
        int xb = x0 + mt * 16 + fh * 4;
        if (MODE == 0) {
            #pragma unroll
            for (int r = 0; r < 4; ++r) {
                float v = acc[mt][r] + bias;
                v = v > 0.f ? v : expm1f(v);
                Yp[((size_t)(y + 1) * 130 + xb + r + 1) * 64 + co0 + fl] = (__hip_bfloat16)v;
            }
        } else {
            float4 o;
            float* op = (float*)&o;
            #pragma unroll
            for (int r = 0; r < 4; ++r) {
                float v = acc[mt][r] + bias;
                op[r] = v > 0.f ? v : expm1f(v);
            }
            *(float4*)&Yo[(size_t)(co0 + fl) * 16384 + y * 128 + xb] = o;
        }
    }
}

// ---------------------------------------------------------------------------
extern "C" void kernel_launch(void* const* d_in, const int* in_sizes, int n_in,
                              void* d_out, int out_size, void* d_ws, size_t ws_size,
                              hipStream_t stream) {
    const float* raw_w  = (const float*)d_in[0];
    const float* mm     = (const float*)d_in[1];
    const float* scores = (const float*)d_in[2];
    const float* w1     = (const float*)d_in[3];
    const float* b1     = (const float*)d_in[4];
    const float* w2     = (const float*)d_in[5];
    const float* b2     = (const float*)d_in[6];
    float* out = (float*)d_out;

    char* ws = (char*)d_ws;
    // Workspace map (live ranges verified disjoint):
    //  [0,32)   Pt                  [32,40)  Wt
    //  [40,41)  Pm+Ps               [41,41.06) Qm,Qi
    //  [41.25,41.5) Wc1,Wc2         [42,58)  Mo (K-half 0)
    //  [58,60.1) Xp                 [61,63.1) Y1p
    //  [64,128) F (fp32, dead after normTransP) -> [64,80) Mo2 (K-half 1)
    __hip_bfloat16* Pt  = (__hip_bfloat16*)ws;                    // 32 MiB
    __hip_bfloat16* Wt  = (__hip_bfloat16*)(ws + (32ull << 20));  // 8 MiB
    float*          Pm  = (float*)(ws + (40ull << 20));           // 512 KiB
    float*          Ps  = (float*)(ws + (40ull << 20) + (512u << 10));
    float*          Qm  = (float*)(ws + (41ull << 20));           // 16 KiB
    float*          Qi  = (float*)(ws + (41ull << 20) + (64u << 10));
    __hip_bfloat16* Wc1 = (__hip_bfloat16*)(ws + (41ull << 20) + (256u << 10));  // 72 KiB
    __hip_bfloat16* Wc2 = (__hip_bfloat16*)(ws + (41ull << 20) + (384u << 10));  // 72 KiB
    float*          Mo  = (float*)(ws + (42ull << 20));           // 16 MiB
    __hip_bfloat16* Xp  = (__hip_bfloat16*)(ws + (58ull << 20));  // 2.07 MiB
    __hip_bfloat16* Y1p = (__hip_bfloat16*)(ws + (61ull << 20));  // 2.07 MiB
    float*          F   = (float*)(ws + (64ull << 20));           // 64 MiB
    float*          Mo2 = (float*)(ws + (64ull << 20));           // 16 MiB (aliases dead F)

    const size_t XP_BYTES = 130ull * 130 * 64 * sizeof(__hip_bfloat16);

    fuseD<<<1024, 256, 0, stream>>>(scores, F);
    transW<<<dim3(16, 64), 256, 0, stream>>>(raw_w, Wt);
    transWc<<<144, 256, 0, stream>>>(w1, Wc1);
    transWc<<<144, 256, 0, stream>>>(w2, Wc2);
    softPart<<<dim3(64, 32), 256, 0, stream>>>(F, mm, Pm, Ps);
    softComb<<<16, 256, 0, stream>>>(Pm, Ps, Qm, Qi);
    normTransP<<<dim3(64, 64), 256, 0, stream>>>(F, mm, Qm, Qi, Pt);
    gemmMfmaK<<<512, 256, 0, stream>>>(Pt, Wt, Mo, Mo2);   // F dead; Mo2 reuses it
    hipMemsetAsync(Xp, 0, XP_BYTES, stream);
    hipMemsetAsync(Y1p, 0, XP_BYTES, stream);
    scatterD<<<4096, 256, 0, stream>>>(Mo, Mo2, Xp);
    convMfma<0><<<256, 256, 0, stream>>>(Xp, Wc1, b1, Y1p, nullptr);
    convMfma<1><<<256, 256, 0, stream>>>(Y1p, Wc2, b2, nullptr, out);
}

// Round 13
// 172.557 us; speedup vs baseline: 1.0279x; 1.0279x over previous
//
#include <hip/hip_runtime.h>
#include <hip/hip_bf16.h>
#include <math.h>

// Problem constants
#define NL 4096     // L patches
#define NQ 4096     // HS*WS pixels
#define SCALE 10.0f

typedef __bf16 bf16x8 __attribute__((ext_vector_type(8)));
typedef float  f32x4  __attribute__((ext_vector_type(4)));
typedef float  f32x4u __attribute__((ext_vector_type(4), aligned(4)));  // 4B-aligned vec load

#define GLOAD_LDS16(gp, lp)                                                        \
    __builtin_amdgcn_global_load_lds((const __attribute__((address_space(1))) void*)(gp), \
                                     (__attribute__((address_space(3))) void*)(lp), \
                                     16, 0, 0)

// ---------------------------------------------------------------------------
// K1: fused double-diagonal pass (round-12 multi-wb structure, verified).
// ---------------------------------------------------------------------------
__global__ __launch_bounds__(256) void fuseD(const float* __restrict__ S,
                                             float* __restrict__ F) {
    int lin = blockIdx.x;
    int blk = (lin & 7) * 128 + (lin >> 3);   // bijective XCD chunking (1024%8==0)
    int l0 = blk * 4;
    int hb = l0 >> 6, wb0 = l0 & 63;          // wb0 in {0,4,...,60}
    int tid = threadIdx.x, lane = tid & 63;

    int rowbase[3]; float wm[3][4];
    #pragma unroll
    for (int d = 0; d < 3; ++d) {
        int h2 = hb + d - 1;
        #pragma unroll
        for (int i = 0; i < 4; ++i) wm[d][i] = 1.f;
        if (h2 >= 0 && h2 <= 63) rowbase[d] = h2 * 64 + wb0;
        else if (h2 < 0) {
            rowbase[d] = 4031 + wb0;
            #pragma unroll
            for (int i = 0; i < 4; ++i) wm[d][i] = (wb0 + i >= 1) ? 1.f : 0.f;
        } else {
            rowbase[d] = 1 + wb0;
            #pragma unroll
            for (int i = 0; i < 4; ++i) wm[d][i] = (wb0 + i <= 62) ? 1.f : 0.f;
        }
    }

    for (int cc = 0; cc < 4; ++cc) {
        int q0 = (cc * 256 + tid) * 4;
        int hs = q0 >> 6, ws0 = q0 & 63;
        f32x4 z4 = {0.f, 0.f, 0.f, 0.f};
        f32x4 acc0 = z4, acc1 = z4, acc2 = z4, acc3 = z4;

        #pragma unroll
        for (int d = 0; d < 3; ++d) {
            int s2 = hs + d - 1;
            bool cw = (s2 < 0) || (s2 > 63);
            int colb = cw ? ((s2 < 0 ? 4031 : 1) + ws0) : (q0 + (d - 1) * 64);
            int cb = cw ? colb - 1 : colb;

            f32x4 v[6], v2[6];
            #pragma unroll
            for (int r = 0; r < 6; ++r) {
                int rr = rowbase[d] - 1 + r;
                v[r] = z4;
                if (rr >= 0 && rr < 4096)
                    v[r] = *(const f32x4u*)(S + (size_t)rr * 4096 + cb);
            }
            if (cw) {
                #pragma unroll
                for (int r = 0; r < 6; ++r) {
                    int rr = rowbase[d] - 1 + r;
                    v2[r] = z4;
                    if (rr >= 0 && rr < 4096)
                        v2[r] = *(const f32x4u*)(S + (size_t)rr * 4096 + colb + 1);
                }
            }

            float lm[4], rm[4];
            #pragma unroll
            for (int r = 0; r < 4; ++r) lm[r] = __shfl_up(v[r][3], 1);
            #pragma unroll
            for (int r = 0; r < 4; ++r) rm[r] = __shfl_down(v[r + 2][0], 1);
            if (!cw) {
                if (lane == 0 || colb == 0) {
                    #pragma unroll
                    for (int r = 0; r < 4; ++r) {
                        int rr = rowbase[d] - 1 + r;
                        lm[r] = (colb > 0 && rr >= 0 && rr < 4096)
                                ? S[(size_t)rr * 4096 + colb - 1] : 0.f;
                    }
                }
                if (lane == 63 || colb + 4 >= 4096) {
                    #pragma unroll
                    for (int r = 0; r < 4; ++r) {
                        int rr = rowbase[d] + 1 + r;
                        rm[r] = (colb + 4 < 4096 && rr >= 0 && rr < 4096)
                                ? S[(size_t)rr * 4096 + colb + 4] : 0.f;
                    }
                }
            }

            f32x4 t[4];
            if (!cw) {
                #pragma unroll
                for (int i = 0; i < 4; ++i) {
                    f32x4 Lv = { lm[i], v[i][0], v[i][1], v[i][2] };
                    f32x4 Cv = v[i + 1];
                    f32x4 Rv = { v[i + 2][1], v[i + 2][2], v[i + 2][3], rm[i] };
                    t[i] = Lv + Cv + Rv;
                }
            } else {
                #pragma unroll
                for (int i = 0; i < 4; ++i) {
                    f32x4 Lv = v[i];
                    f32x4 Cv = { v[i+1][1], v[i+1][2], v[i+1][3], v2[i+1][2] };
                    f32x4 Rv = v2[i + 2];
                    t[i] = Lv + Cv + Rv;
                }
                if (s2 < 0 && ws0 == 0) { t[0][0] = 0.f; t[1][0] = 0.f; t[2][0] = 0.f; t[3][0] = 0.f; }
                if (s2 > 63 && ws0 == 60) { t[0][3] = 0.f; t[1][3] = 0.f; t[2][3] = 0.f; t[3][3] = 0.f; }
            }
            acc0 += wm[d][0] * t[0];
            acc1 += wm[d][1] * t[1];
            acc2 += wm[d][2] * t[2];
            acc3 += wm[d][3] * t[3];
        }
        *(f32x4*)(F + (size_t)(l0 + 0) * 4096 + q0) = acc0;
        *(f32x4*)(F + (size_t)(l0 + 1) * 4096 + q0) = acc1;
        *(f32x4*)(F + (size_t)(l0 + 2) * 4096 + q0) = acc2;
        *(f32x4*)(F + (size_t)(l0 + 3) * 4096 + q0) = acc3;
    }
}

// ---------------------------------------------------------------------------
// S1: partial softmax stats on F[l][q] (column softmax).
// ---------------------------------------------------------------------------
__global__ __launch_bounds__(256) void softPart(const float* __restrict__ F,
                                                const float* __restrict__ mm,
                                                float* __restrict__ Pm,
                                                float* __restrict__ Ps) {
    int qt = blockIdx.x, lc = blockIdx.y;
    int qo = threadIdx.x & 63, lg = threadIdx.x >> 6;
    int q = qt * 64 + qo;
    __shared__ float red[4][64];

    float sv[32];
    float m = -1e30f;
    #pragma unroll
    for (int i = 0; i < 32; ++i) {
        int l = lc * 128 + i * 4 + lg;
        float s = F[(size_t)l * 4096 + q] * mm[l] * SCALE;
        sv[i] = s;
        m = fmaxf(m, s);
    }
    red[lg][qo] = m;
    __syncthreads();
    m = fmaxf(fmaxf(red[0][qo], red[1][qo]), fmaxf(red[2][qo], red[3][qo]));
    __syncthreads();

    float sum = 0.f;
    #pragma unroll
    for (int i = 0; i < 32; ++i) sum += __expf(sv[i] - m);
    red[lg][qo] = sum;
    __syncthreads();
    if (lg == 0) {
        sum = red[0][qo] + red[1][qo] + red[2][qo] + red[3][qo];
        Pm[lc * 4096 + q] = m;
        Ps[lc * 4096 + q] = sum;
    }
}

// ---------------------------------------------------------------------------
// S2: combine 32 chunk partials per q.
// ---------------------------------------------------------------------------
__global__ void softComb(const float* __restrict__ Pm, const float* __restrict__ Ps,
                         float* __restrict__ Qm, float* __restrict__ Qi) {
    int q = blockIdx.x * 256 + threadIdx.x;
    float M = -1e30f;
    #pragma unroll
    for (int i = 0; i < 32; ++i) M = fmaxf(M, Pm[i * 4096 + q]);
    float S = 0.f;
    #pragma unroll
    for (int i = 0; i < 32; ++i) S += Ps[i * 4096 + q] * __expf(Pm[i * 4096 + q] - M);
    Qm[q] = M;
    Qi[q] = 1.0f / S;
}

// ---------------------------------------------------------------------------
// S3: normalize + bf16 convert + transpose. Pt[m=q][k=l] = bf16(P[l][q]).
// ---------------------------------------------------------------------------
__global__ __launch_bounds__(256) void normTransP(const float* __restrict__ F,
                                                  const float* __restrict__ mm,
                                                  const float* __restrict__ Qm,
                                                  const float* __restrict__ Qi,
                                                  __hip_bfloat16* __restrict__ Pt) {
    __shared__ float T[64][65];
    int qt = blockIdx.x, lt = blockIdx.y;
    int c = threadIdx.x & 63;
    int q = qt * 64 + c;
    float qm = Qm[q], qi = Qi[q];
    #pragma unroll
    for (int p = 0; p < 16; ++p) {
        int r = p * 4 + (threadIdx.x >> 6);
        int l = lt * 64 + r;
        float mml = mm[l];
        float s = F[(size_t)l * 4096 + q] * mml * SCALE - qm;
        T[r][c] = mml * __expf(s) * qi;
    }
    __syncthreads();
    #pragma unroll
    for (int p = 0; p < 16; ++p) {
        int r = p * 4 + (threadIdx.x >> 6);
        Pt[(size_t)(qt * 64 + r) * 4096 + lt * 64 + c] = (__hip_bfloat16)T[c][r];
    }
}

// ---------------------------------------------------------------------------
// Wt: transpose + convert raw_w [k][ck] fp32 -> Wt [n][k] bf16, with the
// GEMM N-dim permuted as n = kyx*64 + c (so scatterD reads Mo coalesced).
// ---------------------------------------------------------------------------
__global__ __launch_bounds__(256) void transW(const float* __restrict__ Wsrc,
                                              __hip_bfloat16* __restrict__ Wt) {
    __shared__ float T[64][65];
    int nt = blockIdx.x, kt = blockIdx.y;
    int c = threadIdx.x & 63;
    #pragma unroll
    for (int p = 0; p < 16; ++p) {
        int r = p * 4 + (threadIdx.x >> 6);
        T[r][c] = Wsrc[(size_t)(kt * 64 + r) * 1024 + nt * 64 + c];
    }
    __syncthreads();
    #pragma unroll
    for (int p = 0; p < 16; ++p) {
        int r = p * 4 + (threadIdx.x >> 6);   // r = ck_local; ck = nt*64 + r
        int n_new = (r & 15) * 64 + nt * 4 + (r >> 4);   // kyx*64 + c_chan
        Wt[(size_t)n_new * 4096 + kt * 64 + c] = (__hip_bfloat16)T[c][r];
    }
}

// ---------------------------------------------------------------------------
// Wc prep: conv weight [co][ci][3][3] fp32 -> Wc[kyx][co][ci] bf16.
// ---------------------------------------------------------------------------
__global__ void transWc(const float* __restrict__ Wsrc, __hip_bfloat16* __restrict__ Wd) {
    int t = blockIdx.x * 256 + threadIdx.x;   // kyx*4096 + co*64 + ci
    int kyx = t >> 12;
    int co = (t >> 6) & 63;
    int ci = t & 63;
    Wd[t] = (__hip_bfloat16)Wsrc[co * 576 + ci * 9 + kyx];
}

// ---------------------------------------------------------------------------
// K4: bf16 MFMA GEMM, K-SPLIT x4 (round-13): grid 1024 = 4 blocks/CU =
// 16 waves/CU (occupancy ceiling 50%, was 25%). bn FASTEST within the XCD
// chunk: each XCD phase works on 8 B-panels (4 MB = L2-resident).
// 128x128 tile, BK=32, both-sides XOR swizzle (conflicts=0 verified).
// ---------------------------------------------------------------------------
__global__ __launch_bounds__(256) void gemmMfmaK(const __hip_bfloat16* __restrict__ Ab,
                                                 const __hip_bfloat16* __restrict__ Bb,
                                                 float* __restrict__ C0,
                                                 float* __restrict__ C1,
                                                 float* __restrict__ C2,
                                                 float* __restrict__ C3) {
    __shared__ __align__(16) __hip_bfloat16 As[2][128][32];  // 16 KiB
    __shared__ __align__(16) __hip_bfloat16 Bs[2][128][32];  // 16 KiB
    int lin = blockIdx.x;
    int wid = (lin & 7) * 128 + (lin >> 3);   // bijective XCD chunking (1024%8==0)
    int bz = wid >> 8;                         // 0..3 K-quarter
    int r5 = wid & 255;
    int bn = r5 & 7;                           // bn fastest -> B-panel L2 reuse
    int bm = r5 >> 3;
    int bm0 = bm * 128, bn0 = bn * 128;
    size_t kbase = (size_t)bz * 1024;
    float* Cm = (bz == 0) ? C0 : (bz == 1) ? C1 : (bz == 2) ? C2 : C3;

    int tid = threadIdx.x;
    int lane = tid & 63, w = tid >> 6;
    int wm = (w >> 1) * 64, wn = (w & 1) * 64;

    int srow = w * 32 + (lane >> 2);
    int scol = (((lane & 3) ^ ((lane >> 3) & 3))) * 8;   // swizzled source col
    const __hip_bfloat16* ga0 = Ab + (size_t)(bm0 + srow) * 4096 + kbase + scol;
    const __hip_bfloat16* ga1 = Ab + (size_t)(bm0 + srow + 16) * 4096 + kbase + scol;
    const __hip_bfloat16* gb0 = Bb + (size_t)(bn0 + srow) * 4096 + kbase + scol;
    const __hip_bfloat16* gb1 = Bb + (size_t)(bn0 + srow + 16) * 4096 + kbase + scol;

    f32x4 acc[4][4] = {};
    int fm = lane & 15;
    int fkz = (((lane >> 4) ^ ((lane >> 1) & 3))) * 8;   // swizzled k-offset

    GLOAD_LDS16(ga0, &As[0][w * 32][0]);
    GLOAD_LDS16(ga1, &As[0][w * 32 + 16][0]);
    GLOAD_LDS16(gb0, &Bs[0][w * 32][0]);
    GLOAD_LDS16(gb1, &Bs[0][w * 32 + 16][0]);
    __syncthreads();

    int buf = 0;
    for (int t = 0; t < 32; ++t) {
        if (t + 1 < 32) {
            int k0 = (t + 1) * 32;
            GLOAD_LDS16(ga0 + k0, &As[buf ^ 1][w * 32][0]);
            GLOAD_LDS16(ga1 + k0, &As[buf ^ 1][w * 32 + 16][0]);
            GLOAD_LDS16(gb0 + k0, &Bs[buf ^ 1][w * 32][0]);
            GLOAD_LDS16(gb1 + k0, &Bs[buf ^ 1][w * 32 + 16][0]);
        }
        bf16x8 af[4], bfr[4];
        #pragma unroll
        for (int i = 0; i < 4; ++i)
            af[i] = *(const bf16x8*)&As[buf][wm + i * 16 + fm][fkz];
        #pragma unroll
        for (int j = 0; j < 4; ++j)
            bfr[j] = *(const bf16x8*)&Bs[buf][wn + j * 16 + fm][fkz];
        #pragma unroll
        for (int i = 0; i < 4; ++i)
            #pragma unroll
            for (int j = 0; j < 4; ++j)
                acc[i][j] = __builtin_amdgcn_mfma_f32_16x16x32_bf16(af[i], bfr[j], acc[i][j], 0, 0, 0);
        __syncthreads();
        buf ^= 1;
    }

    // D mapping: col = lane&15, row = (lane>>4)*4 + reg  [HW-verified]
    #pragma unroll
    for (int i = 0; i < 4; ++i) {
        #pragma unroll
        for (int j = 0; j < 4; ++j) {
            int row = bm0 + wm + i * 16 + (lane >> 4) * 4;
            int col = bn0 + wn + j * 16 + (lane & 15);
            #pragma unroll
            for (int r = 0; r < 4; ++r)
                Cm[(size_t)(row + r) * 1024 + col] = acc[i][j][r];
        }
    }
}

// ---------------------------------------------------------------------------
// K5: transposed-conv gather + /4, summing the four K-split quarters ->
// padded NHWC bf16 Xp[130][130][64].
// ---------------------------------------------------------------------------
__global__ void scatterD(const float* __restrict__ Mo, const float* __restrict__ Mo2,
                         const float* __restrict__ Mo3, const float* __restrict__ Mo4,
                         __hip_bfloat16* __restrict__ Xp) {
    int c = threadIdx.x & 63;
    int pix = blockIdx.x * 4 + (threadIdx.x >> 6);
    int ox = pix & 127, oy = pix >> 7;
    float acc = 0.f;
    #pragma unroll
    for (int ky = 0; ky < 4; ++ky) {
        int ty = oy + 1 - ky;
        if (ty & 1) continue;
        int iy = ty >> 1;
        if (iy < 0 || iy >= 64) continue;
        #pragma unroll
        for (int kx = 0; kx < 4; ++kx) {
            int txx = ox + 1 - kx;
            if (txx & 1) continue;
            int ix = txx >> 1;
            if (ix < 0 || ix >= 64) continue;
            size_t off = (size_t)(iy * 64 + ix) * 1024 + (ky * 4 + kx) * 64 + c;
            acc += (Mo[off] + Mo2[off]) + (Mo3[off] + Mo4[off]);
        }
    }
    Xp[((size_t)(oy + 1) * 130 + ox + 1) * 64 + c] = (__hip_bfloat16)(acc * 0.25f);
}

// ---------------------------------------------------------------------------
// K6/K7: 3x3 conv + bias + ELU as 9-offset implicit MFMA GEMM.
// ---------------------------------------------------------------------------
template <int MODE>
__global__ __launch_bounds__(256) void convMfma(const __hip_bfloat16* __restrict__ Xp,
                                                const __hip_bfloat16* __restrict__ Wc,
                                                const float* __restrict__ Bi,
                                                __hip_bfloat16* __restrict__ Yp,
                                                float* __restrict__ Yo) {
    int tid = threadIdx.x, lane = tid & 63, w = tid >> 6;
    int y = blockIdx.x >> 1, x0 = (blockIdx.x & 1) * 64;
    int co0 = w * 16;
    int fl = lane & 15, fh = lane >> 4;

    bf16x8 wb[3][3][2];
    #pragma unroll
    for (int ky = 0; ky < 3; ++ky)
        #pragma unroll
        for (int kx = 0; kx < 3; ++kx)
            #pragma unroll
            for (int kc = 0; kc < 2; ++kc)
                wb[ky][kx][kc] = *(const bf16x8*)&Wc[(size_t)((ky * 3 + kx) * 64 + co0 + fl) * 64 + kc * 32 + fh * 8];

    f32x4 acc[4] = {};
    #pragma unroll
    for (int ky = 0; ky < 3; ++ky) {
        #pragma unroll
        for (int kx = 0; kx < 3; ++kx) {
            const __hip_bfloat16* xrow = Xp + ((size_t)(y + ky) * 130 + x0 + kx) * 64;
            #pragma unroll
            for (int kc = 0; kc < 2; ++kc) {
                #pragma unroll
                for (int mt = 0; mt < 4; ++mt) {
                    bf16x8 af = *(const bf16x8*)&xrow[(mt * 16 + fl) * 64 + kc * 32 + fh * 8];
                    acc[mt] = __builtin_amdgcn_mfma_f32_16x16x32_bf16(af, wb[ky][kx][kc], acc[mt], 0, 0, 0);
                }
            }
        }
    }

    float bias = Bi[co0 + fl];
    #pragma unroll
    for (int mt = 0; mt < 4; ++mt) {
        int xb = x0 + mt * 16 + fh * 4;
        if (MODE == 0) {
            #pragma unroll
            for (int r = 0; r < 4; ++r) {
                float v = acc[mt][r] + bias;
                v = v > 0.f ? v : expm1f(v);
                Yp[((size_t)(y + 1) * 130 + xb + r + 1) * 64 + co0 + fl] = (__hip_bfloat16)v;
            }
        } else {
            float4 o;
            float* op = (float*)&o;
            #pragma unroll
            for (int r = 0; r < 4; ++r) {
                float v = acc[mt][r] + bias;
                op[r] = v > 0.f ? v : expm1f(v);
            }
            *(float4*)&Yo[(size_t)(co0 + fl) * 16384 + y * 128 + xb] = o;
        }
    }
}

// ---------------------------------------------------------------------------
extern "C" void kernel_launch(void* const* d_in, const int* in_sizes, int n_in,
                              void* d_out, int out_size, void* d_ws, size_t ws_size,
                              hipStream_t stream) {
    const float* raw_w  = (const float*)d_in[0];
    const float* mm     = (const float*)d_in[1];
    const float* scores = (const float*)d_in[2];
    const float* w1     = (const float*)d_in[3];
    const float* b1     = (const float*)d_in[4];
    const float* w2     = (const float*)d_in[5];
    const float* b2     = (const float*)d_in[6];
    float* out = (float*)d_out;

    char* ws = (char*)d_ws;
    // Workspace map (live ranges verified disjoint):
    //  [0,32)   Pt                  [32,40)  Wt
    //  [40,41)  Pm+Ps               [41,41.06) Qm,Qi
    //  [41.25,41.5) Wc1,Wc2         [42,58)  Mo (K-quarter 0)
    //  [58,60.1) Xp                 [61,63.1) Y1p
    //  [64,128) F (dead after normTransP) -> Mo2@64, Mo3@80, Mo4@96 (quarters 1-3)
    __hip_bfloat16* Pt  = (__hip_bfloat16*)ws;                    // 32 MiB
    __hip_bfloat16* Wt  = (__hip_bfloat16*)(ws + (32ull << 20));  // 8 MiB
    float*          Pm  = (float*)(ws + (40ull << 20));           // 512 KiB
    float*          Ps  = (float*)(ws + (40ull << 20) + (512u << 10));
    float*          Qm  = (float*)(ws + (41ull << 20));           // 16 KiB
    float*          Qi  = (float*)(ws + (41ull << 20) + (64u << 10));
    __hip_bfloat16* Wc1 = (__hip_bfloat16*)(ws + (41ull << 20) + (256u << 10));  // 72 KiB
    __hip_bfloat16* Wc2 = (__hip_bfloat16*)(ws + (41ull << 20) + (384u << 10));  // 72 KiB
    float*          Mo  = (float*)(ws + (42ull << 20));           // 16 MiB
    __hip_bfloat16* Xp  = (__hip_bfloat16*)(ws + (58ull << 20));  // 2.07 MiB
    __hip_bfloat16* Y1p = (__hip_bfloat16*)(ws + (61ull << 20));  // 2.07 MiB
    float*          F   = (float*)(ws + (64ull << 20));           // 64 MiB
    float*          Mo2 = (float*)(ws + (64ull << 20));           // 16 MiB (aliases dead F)
    float*          Mo3 = (float*)(ws + (80ull << 20));           // 16 MiB
    float*          Mo4 = (float*)(ws + (96ull << 20));           // 16 MiB

    const size_t XP_BYTES = 130ull * 130 * 64 * sizeof(__hip_bfloat16);

    fuseD<<<1024, 256, 0, stream>>>(scores, F);
    transW<<<dim3(16, 64), 256, 0, stream>>>(raw_w, Wt);
    transWc<<<144, 256, 0, stream>>>(w1, Wc1);
    transWc<<<144, 256, 0, stream>>>(w2, Wc2);
    softPart<<<dim3(64, 32), 256, 0, stream>>>(F, mm, Pm, Ps);
    softComb<<<16, 256, 0, stream>>>(Pm, Ps, Qm, Qi);
    normTransP<<<dim3(64, 64), 256, 0, stream>>>(F, mm, Qm, Qi, Pt);
    gemmMfmaK<<<1024, 256, 0, stream>>>(Pt, Wt, Mo, Mo2, Mo3, Mo4);  // F dead
    hipMemsetAsync(Xp, 0, XP_BYTES, stream);
    hipMemsetAsync(Y1p, 0, XP_BYTES, stream);
    scatterD<<<4096, 256, 0, stream>>>(Mo, Mo2, Mo3, Mo4, Xp);
    convMfma<0><<<256, 256, 0, stream>>>(Xp, Wc1, b1, Y1p, nullptr);
    convMfma<1><<<256, 256, 0, stream>>>(Y1p, Wc2, b2, nullptr, out);
}

// Round 14
// 171.587 us; speedup vs baseline: 1.0337x; 1.0056x over previous
//
#include <hip/hip_runtime.h>
#include <hip/hip_bf16.h>
#include <math.h>

// Problem constants
#define NL 4096     // L patches
#define NQ 4096     // HS*WS pixels
#define SCALE 10.0f

typedef __bf16 bf16x8 __attribute__((ext_vector_type(8)));
typedef float  f32x4  __attribute__((ext_vector_type(4)));
typedef float  f32x4u __attribute__((ext_vector_type(4), aligned(4)));  // 4B-aligned vec load

#define GLOAD_LDS16(gp, lp)                                                        \
    __builtin_amdgcn_global_load_lds((const __attribute__((address_space(1))) void*)(gp), \
                                     (__attribute__((address_space(3))) void*)(lp), \
                                     16, 0, 0)

// ---------------------------------------------------------------------------
// K1: fused double-diagonal pass (round-12 multi-wb structure) with the
// round-14 grid split: the former 4-iteration cc loop is now blockIdx.y,
// quadrupling resident blocks (4096 total = up to 7 blocks/CU at VGPR 68)
// to lift the 23.6%-occupancy latency cap seen in round 13.
// ---------------------------------------------------------------------------
__global__ __launch_bounds__(256) void fuseD(const float* __restrict__ S,
                                             float* __restrict__ F) {
    int lin = blockIdx.x;
    int blk = (lin & 7) * 128 + (lin >> 3);   // bijective XCD chunking (1024%8==0)
    int l0 = blk * 4;
    int hb = l0 >> 6, wb0 = l0 & 63;          // wb0 in {0,4,...,60}
    int tid = threadIdx.x, lane = tid & 63;

    int rowbase[3]; float wm[3][4];
    #pragma unroll
    for (int d = 0; d < 3; ++d) {
        int h2 = hb + d - 1;
        #pragma unroll
        for (int i = 0; i < 4; ++i) wm[d][i] = 1.f;
        if (h2 >= 0 && h2 <= 63) rowbase[d] = h2 * 64 + wb0;
        else if (h2 < 0) {
            rowbase[d] = 4031 + wb0;
            #pragma unroll
            for (int i = 0; i < 4; ++i) wm[d][i] = (wb0 + i >= 1) ? 1.f : 0.f;
        } else {
            rowbase[d] = 1 + wb0;
            #pragma unroll
            for (int i = 0; i < 4; ++i) wm[d][i] = (wb0 + i <= 62) ? 1.f : 0.f;
        }
    }

    {
        int q0 = (blockIdx.y * 256 + tid) * 4;
        int hs = q0 >> 6, ws0 = q0 & 63;
        f32x4 z4 = {0.f, 0.f, 0.f, 0.f};
        f32x4 acc0 = z4, acc1 = z4, acc2 = z4, acc3 = z4;

        #pragma unroll
        for (int d = 0; d < 3; ++d) {
            int s2 = hs + d - 1;
            bool cw = (s2 < 0) || (s2 > 63);
            int colb = cw ? ((s2 < 0 ? 4031 : 1) + ws0) : (q0 + (d - 1) * 64);
            int cb = cw ? colb - 1 : colb;

            f32x4 v[6], v2[6];
            #pragma unroll
            for (int r = 0; r < 6; ++r) {
                int rr = rowbase[d] - 1 + r;
                v[r] = z4;
                if (rr >= 0 && rr < 4096)
                    v[r] = *(const f32x4u*)(S + (size_t)rr * 4096 + cb);
            }
            if (cw) {
                #pragma unroll
                for (int r = 0; r < 6; ++r) {
                    int rr = rowbase[d] - 1 + r;
                    v2[r] = z4;
                    if (rr >= 0 && rr < 4096)
                        v2[r] = *(const f32x4u*)(S + (size_t)rr * 4096 + colb + 1);
                }
            }

            float lm[4], rm[4];
            #pragma unroll
            for (int r = 0; r < 4; ++r) lm[r] = __shfl_up(v[r][3], 1);
            #pragma unroll
            for (int r = 0; r < 4; ++r) rm[r] = __shfl_down(v[r + 2][0], 1);
            if (!cw) {
                if (lane == 0 || colb == 0) {
                    #pragma unroll
                    for (int r = 0; r < 4; ++r) {
                        int rr = rowbase[d] - 1 + r;
                        lm[r] = (colb > 0 && rr >= 0 && rr < 4096)
                                ? S[(size_t)rr * 4096 + colb - 1] : 0.f;
                    }
                }
                if (lane == 63 || colb + 4 >= 4096) {
                    #pragma unroll
                    for (int r = 0; r < 4; ++r) {
                        int rr = rowbase[d] + 1 + r;
                        rm[r] = (colb + 4 < 4096 && rr >= 0 && rr < 4096)
                                ? S[(size_t)rr * 4096 + colb + 4] : 0.f;
                    }
                }
            }

            f32x4 t[4];
            if (!cw) {
                #pragma unroll
                for (int i = 0; i < 4; ++i) {
                    f32x4 Lv = { lm[i], v[i][0], v[i][1], v[i][2] };
                    f32x4 Cv = v[i + 1];
                    f32x4 Rv = { v[i + 2][1], v[i + 2][2], v[i + 2][3], rm[i] };
                    t[i] = Lv + Cv + Rv;
                }
            } else {
                #pragma unroll
                for (int i = 0; i < 4; ++i) {
                    f32x4 Lv = v[i];
                    f32x4 Cv = { v[i+1][1], v[i+1][2], v[i+1][3], v2[i+1][2] };
                    f32x4 Rv = v2[i + 2];
                    t[i] = Lv + Cv + Rv;
                }
                if (s2 < 0 && ws0 == 0) { t[0][0] = 0.f; t[1][0] = 0.f; t[2][0] = 0.f; t[3][0] = 0.f; }
                if (s2 > 63 && ws0 == 60) { t[0][3] = 0.f; t[1][3] = 0.f; t[2][3] = 0.f; t[3][3] = 0.f; }
            }
            acc0 += wm[d][0] * t[0];
            acc1 += wm[d][1] * t[1];
            acc2 += wm[d][2] * t[2];
            acc3 += wm[d][3] * t[3];
        }
        *(f32x4*)(F + (size_t)(l0 + 0) * 4096 + q0) = acc0;
        *(f32x4*)(F + (size_t)(l0 + 1) * 4096 + q0) = acc1;
        *(f32x4*)(F + (size_t)(l0 + 2) * 4096 + q0) = acc2;
        *(f32x4*)(F + (size_t)(l0 + 3) * 4096 + q0) = acc3;
    }
}

// ---------------------------------------------------------------------------
// S1: partial softmax stats on F[l][q] (column softmax).
// ---------------------------------------------------------------------------
__global__ __launch_bounds__(256) void softPart(const float* __restrict__ F,
                                                const float* __restrict__ mm,
                                                float* __restrict__ Pm,
                                                float* __restrict__ Ps) {
    int qt = blockIdx.x, lc = blockIdx.y;
    int qo = threadIdx.x & 63, lg = threadIdx.x >> 6;
    int q = qt * 64 + qo;
    __shared__ float red[4][64];

    float sv[32];
    float m = -1e30f;
    #pragma unroll
    for (int i = 0; i < 32; ++i) {
        int l = lc * 128 + i * 4 + lg;
        float s = F[(size_t)l * 4096 + q] * mm[l] * SCALE;
        sv[i] = s;
        m = fmaxf(m, s);
    }
    red[lg][qo] = m;
    __syncthreads();
    m = fmaxf(fmaxf(red[0][qo], red[1][qo]), fmaxf(red[2][qo], red[3][qo]));
    __syncthreads();

    float sum = 0.f;
    #pragma unroll
    for (int i = 0; i < 32; ++i) sum += __expf(sv[i] - m);
    red[lg][qo] = sum;
    __syncthreads();
    if (lg == 0) {
        sum = red[0][qo] + red[1][qo] + red[2][qo] + red[3][qo];
        Pm[lc * 4096 + q] = m;
        Ps[lc * 4096 + q] = sum;
    }
}

// ---------------------------------------------------------------------------
// S2: combine 32 chunk partials per q.
// ---------------------------------------------------------------------------
__global__ void softComb(const float* __restrict__ Pm, const float* __restrict__ Ps,
                         float* __restrict__ Qm, float* __restrict__ Qi) {
    int q = blockIdx.x * 256 + threadIdx.x;
    float M = -1e30f;
    #pragma unroll
    for (int i = 0; i < 32; ++i) M = fmaxf(M, Pm[i * 4096 + q]);
    float S = 0.f;
    #pragma unroll
    for (int i = 0; i < 32; ++i) S += Ps[i * 4096 + q] * __expf(Pm[i * 4096 + q] - M);
    Qm[q] = M;
    Qi[q] = 1.0f / S;
}

// ---------------------------------------------------------------------------
// S3: normalize + bf16 convert + transpose. Pt[m=q][k=l] = bf16(P[l][q]).
// ---------------------------------------------------------------------------
__global__ __launch_bounds__(256) void normTransP(const float* __restrict__ F,
                                                  const float* __restrict__ mm,
                                                  const float* __restrict__ Qm,
                                                  const float* __restrict__ Qi,
                                                  __hip_bfloat16* __restrict__ Pt) {
    __shared__ float T[64][65];
    int qt = blockIdx.x, lt = blockIdx.y;
    int c = threadIdx.x & 63;
    int q = qt * 64 + c;
    float qm = Qm[q], qi = Qi[q];
    #pragma unroll
    for (int p = 0; p < 16; ++p) {
        int r = p * 4 + (threadIdx.x >> 6);
        int l = lt * 64 + r;
        float mml = mm[l];
        float s = F[(size_t)l * 4096 + q] * mml * SCALE - qm;
        T[r][c] = mml * __expf(s) * qi;
    }
    __syncthreads();
    #pragma unroll
    for (int p = 0; p < 16; ++p) {
        int r = p * 4 + (threadIdx.x >> 6);
        Pt[(size_t)(qt * 64 + r) * 4096 + lt * 64 + c] = (__hip_bfloat16)T[c][r];
    }
}

// ---------------------------------------------------------------------------
// Wt: transpose + convert raw_w [k][ck] fp32 -> Wt [n][k] bf16, with the
// GEMM N-dim permuted as n = kyx*64 + c (so scatterD reads Mo coalesced).
// ---------------------------------------------------------------------------
__global__ __launch_bounds__(256) void transW(const float* __restrict__ Wsrc,
                                              __hip_bfloat16* __restrict__ Wt) {
    __shared__ float T[64][65];
    int nt = blockIdx.x, kt = blockIdx.y;
    int c = threadIdx.x & 63;
    #pragma unroll
    for (int p = 0; p < 16; ++p) {
        int r = p * 4 + (threadIdx.x >> 6);
        T[r][c] = Wsrc[(size_t)(kt * 64 + r) * 1024 + nt * 64 + c];
    }
    __syncthreads();
    #pragma unroll
    for (int p = 0; p < 16; ++p) {
        int r = p * 4 + (threadIdx.x >> 6);   // r = ck_local; ck = nt*64 + r
        int n_new = (r & 15) * 64 + nt * 4 + (r >> 4);   // kyx*64 + c_chan
        Wt[(size_t)n_new * 4096 + kt * 64 + c] = (__hip_bfloat16)T[c][r];
    }
}

// ---------------------------------------------------------------------------
// Wc prep: conv weight [co][ci][3][3] fp32 -> Wc[kyx][co][ci] bf16.
// ---------------------------------------------------------------------------
__global__ void transWc(const float* __restrict__ Wsrc, __hip_bfloat16* __restrict__ Wd) {
    int t = blockIdx.x * 256 + threadIdx.x;   // kyx*4096 + co*64 + ci
    int kyx = t >> 12;
    int co = (t >> 6) & 63;
    int ci = t & 63;
    Wd[t] = (__hip_bfloat16)Wsrc[co * 576 + ci * 9 + kyx];
}

// ---------------------------------------------------------------------------
// K4: bf16 MFMA GEMM, K-SPLIT x4. Grid 1024 = 4 blocks/CU; bn fastest within
// the XCD chunk (8 B-panels = 4MB L2-resident). 128x128 tile, BK=32,
// both-sides XOR swizzle (conflicts=0 verified).
// ---------------------------------------------------------------------------
__global__ __launch_bounds__(256) void gemmMfmaK(const __hip_bfloat16* __restrict__ Ab,
                                                 const __hip_bfloat16* __restrict__ Bb,
                                                 float* __restrict__ C0,
                                                 float* __restrict__ C1,
                                                 float* __restrict__ C2,
                                                 float* __restrict__ C3) {
    __shared__ __align__(16) __hip_bfloat16 As[2][128][32];  // 16 KiB
    __shared__ __align__(16) __hip_bfloat16 Bs[2][128][32];  // 16 KiB
    int lin = blockIdx.x;
    int wid = (lin & 7) * 128 + (lin >> 3);   // bijective XCD chunking (1024%8==0)
    int bz = wid >> 8;                         // 0..3 K-quarter
    int r5 = wid & 255;
    int bn = r5 & 7;                           // bn fastest -> B-panel L2 reuse
    int bm = r5 >> 3;
    int bm0 = bm * 128, bn0 = bn * 128;
    size_t kbase = (size_t)bz * 1024;
    float* Cm = (bz == 0) ? C0 : (bz == 1) ? C1 : (bz == 2) ? C2 : C3;

    int tid = threadIdx.x;
    int lane = tid & 63, w = tid >> 6;
    int wm = (w >> 1) * 64, wn = (w & 1) * 64;

    int srow = w * 32 + (lane >> 2);
    int scol = (((lane & 3) ^ ((lane >> 3) & 3))) * 8;   // swizzled source col
    const __hip_bfloat16* ga0 = Ab + (size_t)(bm0 + srow) * 4096 + kbase + scol;
    const __hip_bfloat16* ga1 = Ab + (size_t)(bm0 + srow + 16) * 4096 + kbase + scol;
    const __hip_bfloat16* gb0 = Bb + (size_t)(bn0 + srow) * 4096 + kbase + scol;
    const __hip_bfloat16* gb1 = Bb + (size_t)(bn0 + srow + 16) * 4096 + kbase + scol;

    f32x4 acc[4][4] = {};
    int fm = lane & 15;
    int fkz = (((lane >> 4) ^ ((lane >> 1) & 3))) * 8;   // swizzled k-offset

    GLOAD_LDS16(ga0, &As[0][w * 32][0]);
    GLOAD_LDS16(ga1, &As[0][w * 32 + 16][0]);
    GLOAD_LDS16(gb0, &Bs[0][w * 32][0]);
    GLOAD_LDS16(gb1, &Bs[0][w * 32 + 16][0]);
    __syncthreads();

    int buf = 0;
    for (int t = 0; t < 32; ++t) {
        if (t + 1 < 32) {
            int k0 = (t + 1) * 32;
            GLOAD_LDS16(ga0 + k0, &As[buf ^ 1][w * 32][0]);
            GLOAD_LDS16(ga1 + k0, &As[buf ^ 1][w * 32 + 16][0]);
            GLOAD_LDS16(gb0 + k0, &Bs[buf ^ 1][w * 32][0]);
            GLOAD_LDS16(gb1 + k0, &Bs[buf ^ 1][w * 32 + 16][0]);
        }
        bf16x8 af[4], bfr[4];
        #pragma unroll
        for (int i = 0; i < 4; ++i)
            af[i] = *(const bf16x8*)&As[buf][wm + i * 16 + fm][fkz];
        #pragma unroll
        for (int j = 0; j < 4; ++j)
            bfr[j] = *(const bf16x8*)&Bs[buf][wn + j * 16 + fm][fkz];
        #pragma unroll
        for (int i = 0; i < 4; ++i)
            #pragma unroll
            for (int j = 0; j < 4; ++j)
                acc[i][j] = __builtin_amdgcn_mfma_f32_16x16x32_bf16(af[i], bfr[j], acc[i][j], 0, 0, 0);
        __syncthreads();
        buf ^= 1;
    }

    // D mapping: col = lane&15, row = (lane>>4)*4 + reg  [HW-verified]
    #pragma unroll
    for (int i = 0; i < 4; ++i) {
        #pragma unroll
        for (int j = 0; j < 4; ++j) {
            int row = bm0 + wm + i * 16 + (lane >> 4) * 4;
            int col = bn0 + wn + j * 16 + (lane & 15);
            #pragma unroll
            for (int r = 0; r < 4; ++r)
                Cm[(size_t)(row + r) * 1024 + col] = acc[i][j][r];
        }
    }
}

// ---------------------------------------------------------------------------
// K5: transposed-conv gather + /4, summing the four K-split quarters ->
// padded NHWC bf16 Xp[130][130][64].
// ---------------------------------------------------------------------------
__global__ void scatterD(const float* __restrict__ Mo, const float* __restrict__ Mo2,
                         const float* __restrict__ Mo3, const float* __restrict__ Mo4,
                         __hip_bfloat16* __restrict__ Xp) {
    int c = threadIdx.x & 63;
    int pix = blockIdx.x * 4 + (threadIdx.x >> 6);
    int ox = pix & 127, oy = pix >> 7;
    float acc = 0.f;
    #pragma unroll
    for (int ky = 0; ky < 4; ++ky) {
        int ty = oy + 1 - ky;
        if (ty & 1) continue;
        int iy = ty >> 1;
        if (iy < 0 || iy >= 64) continue;
        #pragma unroll
        for (int kx = 0; kx < 4; ++kx) {
            int txx = ox + 1 - kx;
            if (txx & 1) continue;
            int ix = txx >> 1;
            if (ix < 0 || ix >= 64) continue;
            size_t off = (size_t)(iy * 64 + ix) * 1024 + (ky * 4 + kx) * 64 + c;
            acc += (Mo[off] + Mo2[off]) + (Mo3[off] + Mo4[off]);
        }
    }
    Xp[((size_t)(oy + 1) * 130 + ox + 1) * 64 + c] = (__hip_bfloat16)(acc * 0.25f);
}

// ---------------------------------------------------------------------------
// K6/K7: 3x3 conv + bias + ELU as 9-offset implicit MFMA GEMM.
// ---------------------------------------------------------------------------
template <int MODE>
__global__ __launch_bounds__(256) void convMfma(const __hip_bfloat16* __restrict__ Xp,
                                                const __hip_bfloat16* __restrict__ Wc,
                                                const float* __restrict__ Bi,
                                                __hip_bfloat16* __restrict__ Yp,
                                                float* __restrict__ Yo) {
    int tid = threadIdx.x, lane = tid & 63, w = tid >> 6;
    int y = blockIdx.x >> 1, x0 = (blockIdx.x & 1) * 64;
    int co0 = w * 16;
    int fl = lane & 15, fh = lane >> 4;

    bf16x8 wb[3][3][2];
    #pragma unroll
    for (int ky = 0; ky < 3; ++ky)
        #pragma unroll
        for (int kx = 0; kx < 3; ++kx)
            #pragma unroll
            for (int kc = 0; kc < 2; ++kc)
                wb[ky][kx][kc] = *(const bf16x8*)&Wc[(size_t)((ky * 3 + kx) * 64 + co0 + fl) * 64 + kc * 32 + fh * 8];

    f32x4 acc[4] = {};
    #pragma unroll
    for (int ky = 0; ky < 3; ++ky) {
        #pragma unroll
        for (int kx = 0; kx < 3; ++kx) {
            const __hip_bfloat16* xrow = Xp + ((size_t)(y + ky) * 130 + x0 + kx) * 64;
            #pragma unroll
            for (int kc = 0; kc < 2; ++kc) {
                #pragma unroll
                for (int mt = 0; mt < 4; ++mt) {
                    bf16x8 af = *(const bf16x8*)&xrow[(mt * 16 + fl) * 64 + kc * 32 + fh * 8];
                    acc[mt] = __builtin_amdgcn_mfma_f32_16x16x32_bf16(af, wb[ky][kx][kc], acc[mt], 0, 0, 0);
                }
            }
        }
    }

    float bias = Bi[co0 + fl];
    #pragma unroll
    for (int mt = 0; mt < 4; ++mt) {
        int xb = x0 + mt * 16 + fh * 4;
        if (MODE == 0) {
            #pragma unroll
            for (int r = 0; r < 4; ++r) {
                float v = acc[mt][r] + bias;
                v = v > 0.f ? v : expm1f(v);
                Yp[((size_t)(y + 1) * 130 + xb + r + 1) * 64 + co0 + fl] = (__hip_bfloat16)v;
            }
        } else {
            float4 o;
            float* op = (float*)&o;
            #pragma unroll
            for (int r = 0; r < 4; ++r) {
                float v = acc[mt][r] + bias;
                op[r] = v > 0.f ? v : expm1f(v);
            }
            *(float4*)&Yo[(size_t)(co0 + fl) * 16384 + y * 128 + xb] = o;
        }
    }
}

// ---------------------------------------------------------------------------
extern "C" void kernel_launch(void* const* d_in, const int* in_sizes, int n_in,
                              void* d_out, int out_size, void* d_ws, size_t ws_size,
                              hipStream_t stream) {
    const float* raw_w  = (const float*)d_in[0];
    const float* mm     = (const float*)d_in[1];
    const float* scores = (const float*)d_in[2];
    const float* w1     = (const float*)d_in[3];
    const float* b1     = (const float*)d_in[4];
    const float* w2     = (const float*)d_in[5];
    const float* b2     = (const float*)d_in[6];
    float* out = (float*)d_out;

    char* ws = (char*)d_ws;
    // Workspace map (live ranges verified disjoint):
    //  [0,32)   Pt                  [32,40)  Wt
    //  [40,41)  Pm+Ps               [41,41.06) Qm,Qi
    //  [41.25,41.5) Wc1,Wc2         [42,58)  Mo (K-quarter 0)
    //  [58,60.1) Xp                 [61,63.1) Y1p
    //  [64,128) F (dead after normTransP) -> Mo2@64, Mo3@80, Mo4@96 (quarters 1-3)
    __hip_bfloat16* Pt  = (__hip_bfloat16*)ws;                    // 32 MiB
    __hip_bfloat16* Wt  = (__hip_bfloat16*)(ws + (32ull << 20));  // 8 MiB
    float*          Pm  = (float*)(ws + (40ull << 20));           // 512 KiB
    float*          Ps  = (float*)(ws + (40ull << 20) + (512u << 10));
    float*          Qm  = (float*)(ws + (41ull << 20));           // 16 KiB
    float*          Qi  = (float*)(ws + (41ull << 20) + (64u << 10));
    __hip_bfloat16* Wc1 = (__hip_bfloat16*)(ws + (41ull << 20) + (256u << 10));  // 72 KiB
    __hip_bfloat16* Wc2 = (__hip_bfloat16*)(ws + (41ull << 20) + (384u << 10));  // 72 KiB
    float*          Mo  = (float*)(ws + (42ull << 20));           // 16 MiB
    __hip_bfloat16* Xp  = (__hip_bfloat16*)(ws + (58ull << 20));  // 2.07 MiB
    __hip_bfloat16* Y1p = (__hip_bfloat16*)(ws + (61ull << 20));  // 2.07 MiB
    float*          F   = (float*)(ws + (64ull << 20));           // 64 MiB
    float*          Mo2 = (float*)(ws + (64ull << 20));           // 16 MiB (aliases dead F)
    float*          Mo3 = (float*)(ws + (80ull << 20));           // 16 MiB
    float*          Mo4 = (float*)(ws + (96ull << 20));           // 16 MiB

    const size_t XP_BYTES = 130ull * 130 * 64 * sizeof(__hip_bfloat16);

    fuseD<<<dim3(1024, 4), 256, 0, stream>>>(scores, F);
    transW<<<dim3(16, 64), 256, 0, stream>>>(raw_w, Wt);
    transWc<<<144, 256, 0, stream>>>(w1, Wc1);
    transWc<<<144, 256, 0, stream>>>(w2, Wc2);
    softPart<<<dim3(64, 32), 256, 0, stream>>>(F, mm, Pm, Ps);
    softComb<<<16, 256, 0, stream>>>(Pm, Ps, Qm, Qi);
    normTransP<<<dim3(64, 64), 256, 0, stream>>>(F, mm, Qm, Qi, Pt);
    gemmMfmaK<<<1024, 256, 0, stream>>>(Pt, Wt, Mo, Mo2, Mo3, Mo4);  // F dead
    hipMemsetAsync(Xp, 0, XP_BYTES, stream);
    hipMemsetAsync(Y1p, 0, XP_BYTES, stream);
    scatterD<<<4096, 256, 0, stream>>>(Mo, Mo2, Mo3, Mo4, Xp);
    convMfma<0><<<256, 256, 0, stream>>>(Xp, Wc1, b1, Y1p, nullptr);
    convMfma<1><<<256, 256, 0, stream>>>(Y1p, Wc2, b2, nullptr, out);
}

// Round 15
// 166.724 us; speedup vs baseline: 1.0639x; 1.0292x over previous
//
#include <hip/hip_runtime.h>
#include <hip/hip_bf16.h>
#include <hip/hip_fp16.h>
#include <math.h>

// Problem constants
#define NL 4096     // L patches
#define NQ 4096     // HS*WS pixels
#define SCALE 10.0f

typedef __bf16 bf16x8 __attribute__((ext_vector_type(8)));
typedef float  f32x4  __attribute__((ext_vector_type(4)));
typedef float  f32x4u __attribute__((ext_vector_type(4), aligned(4)));  // 4B-aligned vec load

#define GLOAD_LDS16(gp, lp)                                                        \
    __builtin_amdgcn_global_load_lds((const __attribute__((address_space(1))) void*)(gp), \
                                     (__attribute__((address_space(3))) void*)(lp), \
                                     16, 0, 0)

// ---------------------------------------------------------------------------
// K1: fused double-diagonal pass — round-13 config (measured best: 56.3us).
// ---------------------------------------------------------------------------
__global__ __launch_bounds__(256) void fuseD(const float* __restrict__ S,
                                             float* __restrict__ F) {
    int lin = blockIdx.x;
    int blk = (lin & 7) * 128 + (lin >> 3);   // bijective XCD chunking (1024%8==0)
    int l0 = blk * 4;
    int hb = l0 >> 6, wb0 = l0 & 63;          // wb0 in {0,4,...,60}
    int tid = threadIdx.x, lane = tid & 63;

    int rowbase[3]; float wm[3][4];
    #pragma unroll
    for (int d = 0; d < 3; ++d) {
        int h2 = hb + d - 1;
        #pragma unroll
        for (int i = 0; i < 4; ++i) wm[d][i] = 1.f;
        if (h2 >= 0 && h2 <= 63) rowbase[d] = h2 * 64 + wb0;
        else if (h2 < 0) {
            rowbase[d] = 4031 + wb0;
            #pragma unroll
            for (int i = 0; i < 4; ++i) wm[d][i] = (wb0 + i >= 1) ? 1.f : 0.f;
        } else {
            rowbase[d] = 1 + wb0;
            #pragma unroll
            for (int i = 0; i < 4; ++i) wm[d][i] = (wb0 + i <= 62) ? 1.f : 0.f;
        }
    }

    for (int cc = 0; cc < 4; ++cc) {
        int q0 = (cc * 256 + tid) * 4;
        int hs = q0 >> 6, ws0 = q0 & 63;
        f32x4 z4 = {0.f, 0.f, 0.f, 0.f};
        f32x4 acc0 = z4, acc1 = z4, acc2 = z4, acc3 = z4;

        #pragma unroll
        for (int d = 0; d < 3; ++d) {
            int s2 = hs + d - 1;
            bool cw = (s2 < 0) || (s2 > 63);
            int colb = cw ? ((s2 < 0 ? 4031 : 1) + ws0) : (q0 + (d - 1) * 64);
            int cb = cw ? colb - 1 : colb;

            f32x4 v[6], v2[6];
            #pragma unroll
            for (int r = 0; r < 6; ++r) {
                int rr = rowbase[d] - 1 + r;
                v[r] = z4;
                if (rr >= 0 && rr < 4096)
                    v[r] = *(const f32x4u*)(S + (size_t)rr * 4096 + cb);
            }
            if (cw) {
                #pragma unroll
                for (int r = 0; r < 6; ++r) {
                    int rr = rowbase[d] - 1 + r;
                    v2[r] = z4;
                    if (rr >= 0 && rr < 4096)
                        v2[r] = *(const f32x4u*)(S + (size_t)rr * 4096 + colb + 1);
                }
            }

            float lm[4], rm[4];
            #pragma unroll
            for (int r = 0; r < 4; ++r) lm[r] = __shfl_up(v[r][3], 1);
            #pragma unroll
            for (int r = 0; r < 4; ++r) rm[r] = __shfl_down(v[r + 2][0], 1);
            if (!cw) {
                if (lane == 0 || colb == 0) {
                    #pragma unroll
                    for (int r = 0; r < 4; ++r) {
                        int rr = rowbase[d] - 1 + r;
                        lm[r] = (colb > 0 && rr >= 0 && rr < 4096)
                                ? S[(size_t)rr * 4096 + colb - 1] : 0.f;
                    }
                }
                if (lane == 63 || colb + 4 >= 4096) {
                    #pragma unroll
                    for (int r = 0; r < 4; ++r) {
                        int rr = rowbase[d] + 1 + r;
                        rm[r] = (colb + 4 < 4096 && rr >= 0 && rr < 4096)
                                ? S[(size_t)rr * 4096 + colb + 4] : 0.f;
                    }
                }
            }

            f32x4 t[4];
            if (!cw) {
                #pragma unroll
                for (int i = 0; i < 4; ++i) {
                    f32x4 Lv = { lm[i], v[i][0], v[i][1], v[i][2] };
                    f32x4 Cv = v[i + 1];
                    f32x4 Rv = { v[i + 2][1], v[i + 2][2], v[i + 2][3], rm[i] };
                    t[i] = Lv + Cv + Rv;
                }
            } else {
                #pragma unroll
                for (int i = 0; i < 4; ++i) {
                    f32x4 Lv = v[i];
                    f32x4 Cv = { v[i+1][1], v[i+1][2], v[i+1][3], v2[i+1][2] };
                    f32x4 Rv = v2[i + 2];
                    t[i] = Lv + Cv + Rv;
                }
                if (s2 < 0 && ws0 == 0) { t[0][0] = 0.f; t[1][0] = 0.f; t[2][0] = 0.f; t[3][0] = 0.f; }
                if (s2 > 63 && ws0 == 60) { t[0][3] = 0.f; t[1][3] = 0.f; t[2][3] = 0.f; t[3][3] = 0.f; }
            }
            acc0 += wm[d][0] * t[0];
            acc1 += wm[d][1] * t[1];
            acc2 += wm[d][2] * t[2];
            acc3 += wm[d][3] * t[3];
        }
        *(f32x4*)(F + (size_t)(l0 + 0) * 4096 + q0) = acc0;
        *(f32x4*)(F + (size_t)(l0 + 1) * 4096 + q0) = acc1;
        *(f32x4*)(F + (size_t)(l0 + 2) * 4096 + q0) = acc2;
        *(f32x4*)(F + (size_t)(l0 + 3) * 4096 + q0) = acc3;
    }
}

// ---------------------------------------------------------------------------
// S1: partial softmax stats on F[l][q] (column softmax).
// ---------------------------------------------------------------------------
__global__ __launch_bounds__(256) void softPart(const float* __restrict__ F,
                                                const float* __restrict__ mm,
                                                float* __restrict__ Pm,
                                                float* __restrict__ Ps) {
    int qt = blockIdx.x, lc = blockIdx.y;
    int qo = threadIdx.x & 63, lg = threadIdx.x >> 6;
    int q = qt * 64 + qo;
    __shared__ float red[4][64];

    float sv[32];
    float m = -1e30f;
    #pragma unroll
    for (int i = 0; i < 32; ++i) {
        int l = lc * 128 + i * 4 + lg;
        float s = F[(size_t)l * 4096 + q] * mm[l] * SCALE;
        sv[i] = s;
        m = fmaxf(m, s);
    }
    red[lg][qo] = m;
    __syncthreads();
    m = fmaxf(fmaxf(red[0][qo], red[1][qo]), fmaxf(red[2][qo], red[3][qo]));
    __syncthreads();

    float sum = 0.f;
    #pragma unroll
    for (int i = 0; i < 32; ++i) sum += __expf(sv[i] - m);
    red[lg][qo] = sum;
    __syncthreads();
    if (lg == 0) {
        sum = red[0][qo] + red[1][qo] + red[2][qo] + red[3][qo];
        Pm[lc * 4096 + q] = m;
        Ps[lc * 4096 + q] = sum;
    }
}

// ---------------------------------------------------------------------------
// S2: combine 32 chunk partials per q.
// ---------------------------------------------------------------------------
__global__ void softComb(const float* __restrict__ Pm, const float* __restrict__ Ps,
                         float* __restrict__ Qm, float* __restrict__ Qi) {
    int q = blockIdx.x * 256 + threadIdx.x;
    float M = -1e30f;
    #pragma unroll
    for (int i = 0; i < 32; ++i) M = fmaxf(M, Pm[i * 4096 + q]);
    float S = 0.f;
    #pragma unroll
    for (int i = 0; i < 32; ++i) S += Ps[i * 4096 + q] * __expf(Pm[i * 4096 + q] - M);
    Qm[q] = M;
    Qi[q] = 1.0f / S;
}

// ---------------------------------------------------------------------------
// S3: normalize + bf16 convert + transpose (round-15: vectorized).
// Load: f32x4 from F; compute P in the load phase; store: bf16x4 (uint2).
// T[l_loc][q_loc]; Pt[q][l] = P[l][q]  (mapping identical to prior version).
// ---------------------------------------------------------------------------
__global__ __launch_bounds__(256) void normTransP(const float* __restrict__ F,
                                                  const float* __restrict__ mm,
                                                  const float* __restrict__ Qm,
                                                  const float* __restrict__ Qi,
                                                  __hip_bfloat16* __restrict__ Pt) {
    __shared__ float T[64][65];
    int qt = blockIdx.x, lt = blockIdx.y;
    int t = threadIdx.x;
    int lq = t >> 4;              // 0..15
    int q4 = (t & 15) * 4;        // 0..60
    float4 qm4 = *(const float4*)&Qm[qt * 64 + q4];
    float4 qi4 = *(const float4*)&Qi[qt * 64 + q4];

    #pragma unroll
    for (int p = 0; p < 4; ++p) {
        int l = p * 16 + lq;
        float mml = mm[lt * 64 + l];
        f32x4 v = *(const f32x4*)&F[(size_t)(lt * 64 + l) * 4096 + qt * 64 + q4];
        T[l][q4 + 0] = mml * __expf(v[0] * mml * SCALE - qm4.x) * qi4.x;
        T[l][q4 + 1] = mml * __expf(v[1] * mml * SCALE - qm4.y) * qi4.y;
        T[l][q4 + 2] = mml * __expf(v[2] * mml * SCALE - qm4.z) * qi4.z;
        T[l][q4 + 3] = mml * __expf(v[3] * mml * SCALE - qm4.w) * qi4.w;
    }
    __syncthreads();

    int l4 = (t & 15) * 4;
    #pragma unroll
    for (int p = 0; p < 4; ++p) {
        int ql = p * 16 + (t >> 4);
        __hip_bfloat16 ob[4];
        #pragma unroll
        for (int i = 0; i < 4; ++i) ob[i] = (__hip_bfloat16)T[l4 + i][ql];
        *(uint2*)&Pt[(size_t)(qt * 64 + ql) * 4096 + lt * 64 + l4] = *(const uint2*)ob;
    }
}

// ---------------------------------------------------------------------------
// Wt: transpose + convert raw_w [k][ck] fp32 -> Wt [n][k] bf16, with the
// GEMM N-dim permuted as n = kyx*64 + c (so scatterD reads Mo coalesced).
// ---------------------------------------------------------------------------
__global__ __launch_bounds__(256) void transW(const float* __restrict__ Wsrc,
                                              __hip_bfloat16* __restrict__ Wt) {
    __shared__ float T[64][65];
    int nt = blockIdx.x, kt = blockIdx.y;
    int c = threadIdx.x & 63;
    #pragma unroll
    for (int p = 0; p < 16; ++p) {
        int r = p * 4 + (threadIdx.x >> 6);
        T[r][c] = Wsrc[(size_t)(kt * 64 + r) * 1024 + nt * 64 + c];
    }
    __syncthreads();
    #pragma unroll
    for (int p = 0; p < 16; ++p) {
        int r = p * 4 + (threadIdx.x >> 6);   // r = ck_local; ck = nt*64 + r
        int n_new = (r & 15) * 64 + nt * 4 + (r >> 4);   // kyx*64 + c_chan
        Wt[(size_t)n_new * 4096 + kt * 64 + c] = (__hip_bfloat16)T[c][r];
    }
}

// ---------------------------------------------------------------------------
// Wc prep: conv weight [co][ci][3][3] fp32 -> Wc[kyx][co][ci] bf16.
// ---------------------------------------------------------------------------
__global__ void transWc(const float* __restrict__ Wsrc, __hip_bfloat16* __restrict__ Wd) {
    int t = blockIdx.x * 256 + threadIdx.x;   // kyx*4096 + co*64 + ci
    int kyx = t >> 12;
    int co = (t >> 6) & 63;
    int ci = t & 63;
    Wd[t] = (__hip_bfloat16)Wsrc[co * 576 + ci * 9 + kyx];
}

// ---------------------------------------------------------------------------
// K4: bf16 MFMA GEMM, K-SPLIT x4, fp16 C quarters (round-15: halves the
// C write/read traffic; error ~1e-4 vs 6.25e-3 threshold). Grid 1024 =
// 4 blocks/CU; bn fastest within XCD chunk; both-sides XOR swizzle.
// ---------------------------------------------------------------------------
__global__ __launch_bounds__(256) void gemmMfmaK(const __hip_bfloat16* __restrict__ Ab,
                                                 const __hip_bfloat16* __restrict__ Bb,
                                                 __half* __restrict__ C0,
                                                 __half* __restrict__ C1,
                                                 __half* __restrict__ C2,
                                                 __half* __restrict__ C3) {
    __shared__ __align__(16) __hip_bfloat16 As[2][128][32];  // 16 KiB
    __shared__ __align__(16) __hip_bfloat16 Bs[2][128][32];  // 16 KiB
    int lin = blockIdx.x;
    int wid = (lin & 7) * 128 + (lin >> 3);   // bijective XCD chunking (1024%8==0)
    int bz = wid >> 8;                         // 0..3 K-quarter
    int r5 = wid & 255;
    int bn = r5 & 7;                           // bn fastest -> B-panel L2 reuse
    int bm = r5 >> 3;
    int bm0 = bm * 128, bn0 = bn * 128;
    size_t kbase = (size_t)bz * 1024;
    __half* Cm = (bz == 0) ? C0 : (bz == 1) ? C1 : (bz == 2) ? C2 : C3;

    int tid = threadIdx.x;
    int lane = tid & 63, w = tid >> 6;
    int wm = (w >> 1) * 64, wn = (w & 1) * 64;

    int srow = w * 32 + (lane >> 2);
    int scol = (((lane & 3) ^ ((lane >> 3) & 3))) * 8;   // swizzled source col
    const __hip_bfloat16* ga0 = Ab + (size_t)(bm0 + srow) * 4096 + kbase + scol;
    const __hip_bfloat16* ga1 = Ab + (size_t)(bm0 + srow + 16) * 4096 + kbase + scol;
    const __hip_bfloat16* gb0 = Bb + (size_t)(bn0 + srow) * 4096 + kbase + scol;
    const __hip_bfloat16* gb1 = Bb + (size_t)(bn0 + srow + 16) * 4096 + kbase + scol;

    f32x4 acc[4][4] = {};
    int fm = lane & 15;
    int fkz = (((lane >> 4) ^ ((lane >> 1) & 3))) * 8;   // swizzled k-offset

    GLOAD_LDS16(ga0, &As[0][w * 32][0]);
    GLOAD_LDS16(ga1, &As[0][w * 32 + 16][0]);
    GLOAD_LDS16(gb0, &Bs[0][w * 32][0]);
    GLOAD_LDS16(gb1, &Bs[0][w * 32 + 16][0]);
    __syncthreads();

    int buf = 0;
    for (int t = 0; t < 32; ++t) {
        if (t + 1 < 32) {
            int k0 = (t + 1) * 32;
            GLOAD_LDS16(ga0 + k0, &As[buf ^ 1][w * 32][0]);
            GLOAD_LDS16(ga1 + k0, &As[buf ^ 1][w * 32 + 16][0]);
            GLOAD_LDS16(gb0 + k0, &Bs[buf ^ 1][w * 32][0]);
            GLOAD_LDS16(gb1 + k0, &Bs[buf ^ 1][w * 32 + 16][0]);
        }
        bf16x8 af[4], bfr[4];
        #pragma unroll
        for (int i = 0; i < 4; ++i)
            af[i] = *(const bf16x8*)&As[buf][wm + i * 16 + fm][fkz];
        #pragma unroll
        for (int j = 0; j < 4; ++j)
            bfr[j] = *(const bf16x8*)&Bs[buf][wn + j * 16 + fm][fkz];
        #pragma unroll
        for (int i = 0; i < 4; ++i)
            #pragma unroll
            for (int j = 0; j < 4; ++j)
                acc[i][j] = __builtin_amdgcn_mfma_f32_16x16x32_bf16(af[i], bfr[j], acc[i][j], 0, 0, 0);
        __syncthreads();
        buf ^= 1;
    }

    // D mapping: col = lane&15, row = (lane>>4)*4 + reg  [HW-verified]
    #pragma unroll
    for (int i = 0; i < 4; ++i) {
        #pragma unroll
        for (int j = 0; j < 4; ++j) {
            int row = bm0 + wm + i * 16 + (lane >> 4) * 4;
            int col = bn0 + wn + j * 16 + (lane & 15);
            #pragma unroll
            for (int r = 0; r < 4; ++r)
                Cm[(size_t)(row + r) * 1024 + col] = __float2half(acc[i][j][r]);
        }
    }
}

// ---------------------------------------------------------------------------
// K5: transposed-conv gather + /4, summing the four fp16 K-quarters ->
// padded NHWC bf16 Xp[130][130][64].
// ---------------------------------------------------------------------------
__global__ void scatterD(const __half* __restrict__ Mo, const __half* __restrict__ Mo2,
                         const __half* __restrict__ Mo3, const __half* __restrict__ Mo4,
                         __hip_bfloat16* __restrict__ Xp) {
    int c = threadIdx.x & 63;
    int pix = blockIdx.x * 4 + (threadIdx.x >> 6);
    int ox = pix & 127, oy = pix >> 7;
    float acc = 0.f;
    #pragma unroll
    for (int ky = 0; ky < 4; ++ky) {
        int ty = oy + 1 - ky;
        if (ty & 1) continue;
        int iy = ty >> 1;
        if (iy < 0 || iy >= 64) continue;
        #pragma unroll
        for (int kx = 0; kx < 4; ++kx) {
            int txx = ox + 1 - kx;
            if (txx & 1) continue;
            int ix = txx >> 1;
            if (ix < 0 || ix >= 64) continue;
            size_t off = (size_t)(iy * 64 + ix) * 1024 + (ky * 4 + kx) * 64 + c;
            acc += (__half2float(Mo[off]) + __half2float(Mo2[off]))
                 + (__half2float(Mo3[off]) + __half2float(Mo4[off]));
        }
    }
    Xp[((size_t)(oy + 1) * 130 + ox + 1) * 64 + c] = (__hip_bfloat16)(acc * 0.25f);
}

// ---------------------------------------------------------------------------
// K6/K7: 3x3 conv + bias + ELU as 9-offset implicit MFMA GEMM.
// ---------------------------------------------------------------------------
template <int MODE>
__global__ __launch_bounds__(256) void convMfma(const __hip_bfloat16* __restrict__ Xp,
                                                const __hip_bfloat16* __restrict__ Wc,
                                                const float* __restrict__ Bi,
                                                __hip_bfloat16* __restrict__ Yp,
                                                float* __restrict__ Yo) {
    int tid = threadIdx.x, lane = tid & 63, w = tid >> 6;
    int y = blockIdx.x >> 1, x0 = (blockIdx.x & 1) * 64;
    int co0 = w * 16;
    int fl = lane & 15, fh = lane >> 4;

    bf16x8 wb[3][3][2];
    #pragma unroll
    for (int ky = 0; ky < 3; ++ky)
        #pragma unroll
        for (int kx = 0; kx < 3; ++kx)
            #pragma unroll
            for (int kc = 0; kc < 2; ++kc)
                wb[ky][kx][kc] = *(const bf16x8*)&Wc[(size_t)((ky * 3 + kx) * 64 + co0 + fl) * 64 + kc * 32 + fh * 8];

    f32x4 acc[4] = {};
    #pragma unroll
    for (int ky = 0; ky < 3; ++ky) {
        #pragma unroll
        for (int kx = 0; kx < 3; ++kx) {
            const __hip_bfloat16* xrow = Xp + ((size_t)(y + ky) * 130 + x0 + kx) * 64;
            #pragma unroll
            for (int kc = 0; kc < 2; ++kc) {
                #pragma unroll
                for (int mt = 0; mt < 4; ++mt) {
                    bf16x8 af = *(const bf16x8*)&xrow[(mt * 16 + fl) * 64 + kc * 32 + fh * 8];
                    acc[mt] = __builtin_amdgcn_mfma_f32_16x16x32_bf16(af, wb[ky][kx][kc], acc[mt], 0, 0, 0);
                }
            }
        }
    }

    float bias = Bi[co0 + fl];
    #pragma unroll
    for (int mt = 0; mt < 4; ++mt) {
        int xb = x0 + mt * 16 + fh * 4;
        if (MODE == 0) {
            #pragma unroll
            for (int r = 0; r < 4; ++r) {
                float v = acc[mt][r] + bias;
                v = v > 0.f ? v : expm1f(v);
                Yp[((size_t)(y + 1) * 130 + xb + r + 1) * 64 + co0 + fl] = (__hip_bfloat16)v;
            }
        } else {
            float4 o;
            float* op = (float*)&o;
            #pragma unroll
            for (int r = 0; r < 4; ++r) {
                float v = acc[mt][r] + bias;
                op[r] = v > 0.f ? v : expm1f(v);
            }
            *(float4*)&Yo[(size_t)(co0 + fl) * 16384 + y * 128 + xb] = o;
        }
    }
}

// ---------------------------------------------------------------------------
extern "C" void kernel_launch(void* const* d_in, const int* in_sizes, int n_in,
                              void* d_out, int out_size, void* d_ws, size_t ws_size,
                              hipStream_t stream) {
    const float* raw_w  = (const float*)d_in[0];
    const float* mm     = (const float*)d_in[1];
    const float* scores = (const float*)d_in[2];
    const float* w1     = (const float*)d_in[3];
    const float* b1     = (const float*)d_in[4];
    const float* w2     = (const float*)d_in[5];
    const float* b2     = (const float*)d_in[6];
    float* out = (float*)d_out;

    char* ws = (char*)d_ws;
    // Workspace map (live ranges verified disjoint):
    //  [0,32)   Pt                  [32,40)  Wt
    //  [40,41)  Pm+Ps               [41,41.06) Qm,Qi
    //  [41.25,41.5) Wc1,Wc2         [42,50) Mo q0 (fp16 8MB)  [50,58) Mo2
    //  [58,60.1) Xp                 [61,63.1) Y1p
    //  [64,128) F (dead after normTransP) -> Mo3@64, Mo4@72 (fp16 quarters)
    __hip_bfloat16* Pt  = (__hip_bfloat16*)ws;                    // 32 MiB
    __hip_bfloat16* Wt  = (__hip_bfloat16*)(ws + (32ull << 20));  // 8 MiB
    float*          Pm  = (float*)(ws + (40ull << 20));           // 512 KiB
    float*          Ps  = (float*)(ws + (40ull << 20) + (512u << 10));
    float*          Qm  = (float*)(ws + (41ull << 20));           // 16 KiB
    float*          Qi  = (float*)(ws + (41ull << 20) + (64u << 10));
    __hip_bfloat16* Wc1 = (__hip_bfloat16*)(ws + (41ull << 20) + (256u << 10));  // 72 KiB
    __hip_bfloat16* Wc2 = (__hip_bfloat16*)(ws + (41ull << 20) + (384u << 10));  // 72 KiB
    __half*         Mo  = (__half*)(ws + (42ull << 20));          // 8 MiB
    __half*         Mo2 = (__half*)(ws + (50ull << 20));          // 8 MiB
    __hip_bfloat16* Xp  = (__hip_bfloat16*)(ws + (58ull << 20));  // 2.07 MiB
    __hip_bfloat16* Y1p = (__hip_bfloat16*)(ws + (61ull << 20));  // 2.07 MiB
    float*          F   = (float*)(ws + (64ull << 20));           // 64 MiB
    __half*         Mo3 = (__half*)(ws + (64ull << 20));          // 8 MiB (aliases dead F)
    __half*         Mo4 = (__half*)(ws + (72ull << 20));          // 8 MiB

    const size_t XP_BYTES = 130ull * 130 * 64 * sizeof(__hip_bfloat16);

    fuseD<<<1024, 256, 0, stream>>>(scores, F);
    transW<<<dim3(16, 64), 256, 0, stream>>>(raw_w, Wt);
    transWc<<<144, 256, 0, stream>>>(w1, Wc1);
    transWc<<<144, 256, 0, stream>>>(w2, Wc2);
    softPart<<<dim3(64, 32), 256, 0, stream>>>(F, mm, Pm, Ps);
    softComb<<<16, 256, 0, stream>>>(Pm, Ps, Qm, Qi);
    normTransP<<<dim3(64, 64), 256, 0, stream>>>(F, mm, Qm, Qi, Pt);
    gemmMfmaK<<<1024, 256, 0, stream>>>(Pt, Wt, Mo, Mo2, Mo3, Mo4);  // F dead
    hipMemsetAsync(Xp, 0, XP_BYTES, stream);
    hipMemsetAsync(Y1p, 0, XP_BYTES, stream);
    scatterD<<<4096, 256, 0, stream>>>(Mo, Mo2, Mo3, Mo4, Xp);
    convMfma<0><<<256, 256, 0, stream>>>(Xp, Wc1, b1, Y1p, nullptr);
    convMfma<1><<<256, 256, 0, stream>>>(Y1p, Wc2, b2, nullptr, out);
}